// Round 1
// baseline (141.162 us; speedup 1.0000x reference)
//
#include <hip/hip_runtime.h>

typedef __attribute__((ext_vector_type(8))) short short8;
typedef __attribute__((ext_vector_type(4))) float f32x4;

#define NB 8
#define NC 256
#define NH 4
#define ND 64
#define NN 1024
#define OC3 768

__device__ __forceinline__ unsigned short f2bf(float f) {
  union { float f; unsigned int u; } a;
  a.f = f;
  unsigned int r = a.u + 0x7fffu + ((a.u >> 16) & 1u);
  return (unsigned short)(r >> 16);
}

// ---------------------------------------------------------------------------
// transpose + cast: in (batch, R, S) fp32  ->  out (batch, S, R) bf16
// 64x64 tiles through LDS (pitch 65 -> conflict-free), coalesced both sides.
// ---------------------------------------------------------------------------
__global__ __launch_bounds__(256) void transpose_cast(
    const float* __restrict__ in, unsigned short* __restrict__ out, int R, int S) {
  __shared__ float T[64][65];
  int s0 = blockIdx.x * 64, r0 = blockIdx.y * 64;
  const float* inb = in + (size_t)blockIdx.z * R * S;
  unsigned short* outb = out + (size_t)blockIdx.z * R * S;
  int t = threadIdx.x;
  {
    int ri = t >> 2, sb = t & 3;
    const float* p = inb + (size_t)(r0 + ri) * S + s0 + sb * 16;
    float4 v0 = *(const float4*)(p);
    float4 v1 = *(const float4*)(p + 4);
    float4 v2 = *(const float4*)(p + 8);
    float4 v3 = *(const float4*)(p + 12);
    float vv[16] = {v0.x, v0.y, v0.z, v0.w, v1.x, v1.y, v1.z, v1.w,
                    v2.x, v2.y, v2.z, v2.w, v3.x, v3.y, v3.z, v3.w};
#pragma unroll
    for (int e = 0; e < 16; ++e) T[ri][sb * 16 + e] = vv[e];
  }
  __syncthreads();
  {
    int so = t >> 2, rb = t & 3;
    union { unsigned short us[16]; uint4 v[2]; } pk;
#pragma unroll
    for (int e = 0; e < 16; ++e) pk.us[e] = f2bf(T[rb * 16 + e][so]);
    uint4* dst = (uint4*)(outb + (size_t)(s0 + so) * R + r0 + rb * 16);
    dst[0] = pk.v[0];
    dst[1] = pk.v[1];
  }
}

// ---------------------------------------------------------------------------
// GEMM1: qkv = xs(8192x256) @ Wp(256x768) + bp.  A=xs bf16 row-major,
// B=WpT (768x256, N-major) bf16.  64x64 tile/block, BK=64, 4 waves.
// N-tiles are type-pure (o0%192 in {0,64,128} -> Q, K, V).
// Q pre-scaled by 1/sqrt(D)=0.125.  V written transposed: Vt[b][h][d][n].
// ---------------------------------------------------------------------------
__global__ __launch_bounds__(256) void gemm_qkv(
    const unsigned short* __restrict__ xs, const unsigned short* __restrict__ WpT,
    const float* __restrict__ bp,
    unsigned short* __restrict__ Q, unsigned short* __restrict__ K,
    unsigned short* __restrict__ Vt) {
  __shared__ __attribute__((aligned(16))) unsigned short Al[64 * 72];
  __shared__ __attribute__((aligned(16))) unsigned short Bl[64 * 72];
  __shared__ __attribute__((aligned(16))) unsigned short Tl[64 * 72];
  int nt = blockIdx.x, mt = blockIdx.y;
  int t = threadIdx.x, w = t >> 6, l = t & 63, q = l >> 4, c = l & 15;
  f32x4 acc[4] = {{0, 0, 0, 0}, {0, 0, 0, 0}, {0, 0, 0, 0}, {0, 0, 0, 0}};
  const unsigned short* Arow = xs + (size_t)(mt * 64) * NC;
  const unsigned short* Brow = WpT + (size_t)(nt * 64) * NC;
  for (int k0 = 0; k0 < NC; k0 += 64) {
    __syncthreads();
#pragma unroll
    for (int it = 0; it < 2; ++it) {
      int u = t + it * 256;
      int row = u >> 3, kb = u & 7;
      *(uint4*)&Al[row * 72 + kb * 8] = *(const uint4*)(Arow + (size_t)row * NC + k0 + kb * 8);
      *(uint4*)&Bl[row * 72 + kb * 8] = *(const uint4*)(Brow + (size_t)row * NC + k0 + kb * 8);
    }
    __syncthreads();
#pragma unroll
    for (int ks = 0; ks < 2; ++ks) {
      short8 a = *(const short8*)&Al[(w * 16 + c) * 72 + ks * 32 + q * 8];
#pragma unroll
      for (int ct = 0; ct < 4; ++ct) {
        short8 b = *(const short8*)&Bl[(ct * 16 + c) * 72 + ks * 32 + q * 8];
        acc[ct] = __builtin_amdgcn_mfma_f32_16x16x32_bf16(a, b, acc[ct], 0, 0, 0);
      }
    }
  }
  int o0 = nt * 64;
  int h = o0 / 192, rem = o0 % 192;
  int b = (mt * 64) >> 10, n0 = (mt * 64) & 1023;
#pragma unroll
  for (int ct = 0; ct < 4; ++ct) {
    float bias = bp[o0 + ct * 16 + c];
#pragma unroll
    for (int r = 0; r < 4; ++r) acc[ct][r] += bias;
  }
  if (rem < 128) {
    unsigned short* dst = (rem == 0) ? Q : K;
    float sc = (rem == 0) ? 0.125f : 1.0f;
    size_t base = (size_t)(b * NH + h) * NN;
#pragma unroll
    for (int ct = 0; ct < 4; ++ct)
#pragma unroll
      for (int r = 0; r < 4; ++r) {
        int n = n0 + w * 16 + q * 4 + r;
        dst[(base + n) * ND + ct * 16 + c] = f2bf(acc[ct][r] * sc);
      }
  } else {
    // V: transpose 64x64 tile through LDS, store Vt[b][h][d][n] coalesced.
#pragma unroll
    for (int ct = 0; ct < 4; ++ct)
#pragma unroll
      for (int r = 0; r < 4; ++r)
        Tl[(ct * 16 + c) * 72 + (w * 16 + q * 4 + r)] = f2bf(acc[ct][r]);
    __syncthreads();
    size_t base = (size_t)(b * NH + h) * ND * NN;
#pragma unroll
    for (int it = 0; it < 2; ++it) {
      int u = t + it * 256;
      int d = u >> 3, nb = u & 7;
      *(uint4*)(Vt + base + (size_t)d * NN + n0 + nb * 8) = *(const uint4*)&Tl[d * 72 + nb * 8];
    }
  }
}

// ---------------------------------------------------------------------------
// Flash attention per (b,h,i-tile of 64 Q rows). 4 waves x 16 rows.
// S-tile = Q Kt via MFMA (Q pre-scaled); online softmax (rows = quad*4+reg,
// width-16 shfl reductions); P -> LDS (A-operand layout); O += P V with
// B-fragments from the pre-transposed Vt tile. Output O bf16 (B,N,256).
// ---------------------------------------------------------------------------
__global__ __launch_bounds__(256) void attn(
    const unsigned short* __restrict__ Q, const unsigned short* __restrict__ K,
    const unsigned short* __restrict__ Vt, unsigned short* __restrict__ O) {
  __shared__ __attribute__((aligned(16))) unsigned short Ql[64 * 72];
  __shared__ __attribute__((aligned(16))) unsigned short Kl[64 * 72];
  __shared__ __attribute__((aligned(16))) unsigned short Vl[64 * 72];
  __shared__ __attribute__((aligned(16))) unsigned short Pl[4 * 16 * 72];
  int bh = blockIdx.y;
  int b = bh >> 2, h = bh & 3;
  int i0 = blockIdx.x * 64;
  int t = threadIdx.x, w = t >> 6, l = t & 63, q = l >> 4, c = l & 15;
  const unsigned short* Qb = Q + (size_t)bh * NN * ND;
  const unsigned short* Kb = K + (size_t)bh * NN * ND;
  const unsigned short* Vb = Vt + (size_t)bh * ND * NN;
#pragma unroll
  for (int s = 0; s < 2; ++s) {
    int u = t + s * 256;
    int row = u >> 3, kb = u & 7;
    *(uint4*)&Ql[row * 72 + kb * 8] = *(const uint4*)(Qb + (size_t)(i0 + row) * ND + kb * 8);
  }
  __syncthreads();
  short8 aq0 = *(const short8*)&Ql[(w * 16 + c) * 72 + q * 8];
  short8 aq1 = *(const short8*)&Ql[(w * 16 + c) * 72 + 32 + q * 8];
  float m_run[4], l_run[4];
#pragma unroll
  for (int r = 0; r < 4; ++r) { m_run[r] = -1e30f; l_run[r] = 0.f; }
  f32x4 oacc[4] = {{0, 0, 0, 0}, {0, 0, 0, 0}, {0, 0, 0, 0}, {0, 0, 0, 0}};
  unsigned short* pw = &Pl[w * 16 * 72];
  for (int jt = 0; jt < 16; ++jt) {
    __syncthreads();
#pragma unroll
    for (int s = 0; s < 2; ++s) {
      int u = t + s * 256;
      int row = u >> 3, kb = u & 7;
      *(uint4*)&Kl[row * 72 + kb * 8] =
          *(const uint4*)(Kb + (size_t)(jt * 64 + row) * ND + kb * 8);
      *(uint4*)&Vl[row * 72 + kb * 8] =
          *(const uint4*)(Vb + (size_t)row * NN + jt * 64 + kb * 8);
    }
    __syncthreads();
    f32x4 sa[4] = {{0, 0, 0, 0}, {0, 0, 0, 0}, {0, 0, 0, 0}, {0, 0, 0, 0}};
#pragma unroll
    for (int ks = 0; ks < 2; ++ks) {
      short8 a = ks ? aq1 : aq0;
#pragma unroll
      for (int js = 0; js < 4; ++js) {
        short8 bk = *(const short8*)&Kl[(js * 16 + c) * 72 + ks * 32 + q * 8];
        sa[js] = __builtin_amdgcn_mfma_f32_16x16x32_bf16(a, bk, sa[js], 0, 0, 0);
      }
    }
    float mnew[4], alpha[4];
#pragma unroll
    for (int r = 0; r < 4; ++r) {
      float tm = fmaxf(fmaxf(sa[0][r], sa[1][r]), fmaxf(sa[2][r], sa[3][r]));
      tm = fmaxf(tm, __shfl_xor(tm, 1));
      tm = fmaxf(tm, __shfl_xor(tm, 2));
      tm = fmaxf(tm, __shfl_xor(tm, 4));
      tm = fmaxf(tm, __shfl_xor(tm, 8));
      mnew[r] = fmaxf(m_run[r], tm);
      alpha[r] = __expf(m_run[r] - mnew[r]);
    }
#pragma unroll
    for (int js = 0; js < 4; ++js)
#pragma unroll
      for (int r = 0; r < 4; ++r) sa[js][r] = __expf(sa[js][r] - mnew[r]);
#pragma unroll
    for (int r = 0; r < 4; ++r) {
      float ps = sa[0][r] + sa[1][r] + sa[2][r] + sa[3][r];
      ps += __shfl_xor(ps, 1);
      ps += __shfl_xor(ps, 2);
      ps += __shfl_xor(ps, 4);
      ps += __shfl_xor(ps, 8);
      l_run[r] = l_run[r] * alpha[r] + ps;
      m_run[r] = mnew[r];
    }
#pragma unroll
    for (int dt = 0; dt < 4; ++dt)
#pragma unroll
      for (int r = 0; r < 4; ++r) oacc[dt][r] *= alpha[r];
    // P (this wave's 16x64) to LDS in row-major, re-read as A-fragments.
#pragma unroll
    for (int js = 0; js < 4; ++js)
#pragma unroll
      for (int r = 0; r < 4; ++r)
        pw[(q * 4 + r) * 72 + js * 16 + c] = f2bf(sa[js][r]);
#pragma unroll
    for (int ks = 0; ks < 2; ++ks) {
      short8 pa = *(const short8*)&pw[c * 72 + ks * 32 + q * 8];
#pragma unroll
      for (int dt = 0; dt < 4; ++dt) {
        short8 bv = *(const short8*)&Vl[(dt * 16 + c) * 72 + ks * 32 + q * 8];
        oacc[dt] = __builtin_amdgcn_mfma_f32_16x16x32_bf16(pa, bv, oacc[dt], 0, 0, 0);
      }
    }
  }
  float inv[4];
#pragma unroll
  for (int r = 0; r < 4; ++r) inv[r] = 1.0f / l_run[r];
  size_t nbase = (size_t)b * NN + i0 + w * 16;
#pragma unroll
  for (int dt = 0; dt < 4; ++dt)
#pragma unroll
    for (int r = 0; r < 4; ++r)
      O[(nbase + q * 4 + r) * NC + h * ND + dt * 16 + c] = f2bf(oacc[dt][r] * inv[r]);
}

// ---------------------------------------------------------------------------
// GEMM2: res = O(8192x256) @ Wo(256x256) + bo; out[b][c][n] = res + x[b][c][n]
// (fused residual + transpose through LDS, fp32 output, coalesced float4).
// ---------------------------------------------------------------------------
__global__ __launch_bounds__(256) void gemm_out(
    const unsigned short* __restrict__ O, const unsigned short* __restrict__ WoT,
    const float* __restrict__ bo, const float* __restrict__ x,
    float* __restrict__ out) {
  __shared__ __attribute__((aligned(16))) unsigned short Al[64 * 72];
  __shared__ __attribute__((aligned(16))) unsigned short Bl[64 * 72];
  __shared__ float Tl[64 * 65];
  int nt = blockIdx.x, mt = blockIdx.y;
  int t = threadIdx.x, w = t >> 6, l = t & 63, q = l >> 4, c = l & 15;
  f32x4 acc[4] = {{0, 0, 0, 0}, {0, 0, 0, 0}, {0, 0, 0, 0}, {0, 0, 0, 0}};
  const unsigned short* Arow = O + (size_t)(mt * 64) * NC;
  const unsigned short* Brow = WoT + (size_t)(nt * 64) * NC;
  for (int k0 = 0; k0 < NC; k0 += 64) {
    __syncthreads();
#pragma unroll
    for (int it = 0; it < 2; ++it) {
      int u = t + it * 256;
      int row = u >> 3, kb = u & 7;
      *(uint4*)&Al[row * 72 + kb * 8] = *(const uint4*)(Arow + (size_t)row * NC + k0 + kb * 8);
      *(uint4*)&Bl[row * 72 + kb * 8] = *(const uint4*)(Brow + (size_t)row * NC + k0 + kb * 8);
    }
    __syncthreads();
#pragma unroll
    for (int ks = 0; ks < 2; ++ks) {
      short8 a = *(const short8*)&Al[(w * 16 + c) * 72 + ks * 32 + q * 8];
#pragma unroll
      for (int ct = 0; ct < 4; ++ct) {
        short8 b = *(const short8*)&Bl[(ct * 16 + c) * 72 + ks * 32 + q * 8];
        acc[ct] = __builtin_amdgcn_mfma_f32_16x16x32_bf16(a, b, acc[ct], 0, 0, 0);
      }
    }
  }
#pragma unroll
  for (int ct = 0; ct < 4; ++ct) {
    float bias = bo[nt * 64 + ct * 16 + c];
#pragma unroll
    for (int r = 0; r < 4; ++r)
      Tl[(ct * 16 + c) * 65 + w * 16 + q * 4 + r] = acc[ct][r] + bias;
  }
  __syncthreads();
  int b = (mt * 64) >> 10, n0 = (mt * 64) & 1023;
  int cl = t >> 2, nb = t & 3;
  float v[16];
#pragma unroll
  for (int e = 0; e < 16; ++e) v[e] = Tl[cl * 65 + nb * 16 + e];
  size_t base = ((size_t)(b * NC + nt * 64 + cl)) * NN + n0 + nb * 16;
#pragma unroll
  for (int g = 0; g < 4; ++g) {
    float4 xv = *(const float4*)(x + base + g * 4);
    float4 ov;
    ov.x = v[g * 4 + 0] + xv.x;
    ov.y = v[g * 4 + 1] + xv.y;
    ov.z = v[g * 4 + 2] + xv.z;
    ov.w = v[g * 4 + 3] + xv.w;
    *(float4*)(out + base + g * 4) = ov;
  }
}

// ---------------------------------------------------------------------------
extern "C" void kernel_launch(void* const* d_in, const int* in_sizes, int n_in,
                              void* d_out, int out_size, void* d_ws, size_t ws_size,
                              hipStream_t stream) {
  const float* x = (const float*)d_in[0];
  const float* Wp = (const float*)d_in[1];
  const float* bp = (const float*)d_in[2];
  const float* Wo = (const float*)d_in[3];
  const float* bo = (const float*)d_in[4];
  float* out = (float*)d_out;
  char* ws = (char*)d_ws;
  // workspace layout (bytes), total 21,495,808
  unsigned short* xs  = (unsigned short*)(ws);             // 4 MB  (B,N,C) bf16
  unsigned short* WpT = (unsigned short*)(ws + 4194304);   // 384KB (768,256)
  unsigned short* WoT = (unsigned short*)(ws + 4587520);   // 128KB (256,256)
  unsigned short* Qb  = (unsigned short*)(ws + 4718592);   // 4 MB  (B,H,N,D)
  unsigned short* Kb  = (unsigned short*)(ws + 8912896);   // 4 MB  (B,H,N,D)
  unsigned short* Vt  = (unsigned short*)(ws + 13107200);  // 4 MB  (B,H,D,N)
  unsigned short* Ob  = (unsigned short*)(ws + 17301504);  // 4 MB  (B,N,C)

  hipLaunchKernelGGL(transpose_cast, dim3(16, 4, 8), dim3(256), 0, stream, x, xs, NC, NN);
  hipLaunchKernelGGL(transpose_cast, dim3(12, 4, 1), dim3(256), 0, stream, Wp, WpT, NC, OC3);
  hipLaunchKernelGGL(transpose_cast, dim3(4, 4, 1), dim3(256), 0, stream, Wo, WoT, NC, NC);
  hipLaunchKernelGGL(gemm_qkv, dim3(12, 128), dim3(256), 0, stream, xs, WpT, bp, Qb, Kb, Vt);
  hipLaunchKernelGGL(attn, dim3(16, 32), dim3(256), 0, stream, Qb, Kb, Vt, Ob);
  hipLaunchKernelGGL(gemm_out, dim3(4, 128), dim3(256), 0, stream, Ob, WoT, bo, x, out);
}